// Round 1
// 223.840 us; speedup vs baseline: 1.0182x; 1.0182x over previous
//
#include <hip/hip_runtime.h>
#include <stdint.h>

// ---------------------------------------------------------------------------
// DualGatedRecurrence on MI355X.
// fwht() in the reference is the identity for D=1024 => hproj(x,s) = x*prod(s).
// Pipeline (4 dispatches):
//   scanA+prep: per-chunk local scans -> P,H aggregates; weight prep to bf16.
//   scanC: carry prefix + full rescan; emits xb (bf16 x) and hcat bf16.
//   GEMM1/GEMM2: 8-phase 256-wide-tile bf16 MFMA schedule (T3+T4 counted
//     vmcnt, T5 setprio, XOR-swizzled LDS; 8 waves 2Mx4N; dbuf 128/96 KB).
//     GEMM1 epilogue: sigmoid*hcat + rowsum atomics. GEMM2: rsqrt row scale.
// ---------------------------------------------------------------------------

typedef __attribute__((ext_vector_type(8))) short short8;     // 8 bf16
typedef __attribute__((ext_vector_type(4))) float f32x4;
typedef __attribute__((ext_vector_type(2))) float f32x2;
typedef __attribute__((ext_vector_type(4))) unsigned short ushort4v;
typedef __attribute__((ext_vector_type(2))) unsigned short ushort2v;

typedef const __attribute__((address_space(1))) unsigned int* as1_u32p;
typedef __attribute__((address_space(3))) unsigned int* as3_u32p;

__device__ __forceinline__ void cp16(const void* g, void* l) {
  __builtin_amdgcn_global_load_lds((as1_u32p)(uintptr_t)g,
                                   (as3_u32p)(unsigned int)(uintptr_t)l,
                                   16, 0, 0);
}

__device__ __forceinline__ float b2f(unsigned short h) {
  union { unsigned int u; float f; } v; v.u = ((unsigned int)h) << 16; return v.f;
}
__device__ __forceinline__ unsigned short f2b(float f) {
  union { float f; unsigned int u; } v; v.f = f;
  unsigned int r = v.u + 0x7fffu + ((v.u >> 16) & 1u);   // round-nearest-even
  return (unsigned short)(r >> 16);
}
__device__ __forceinline__ float sigmoidf_(float z) {
  return __builtin_amdgcn_rcpf(1.0f + __expf(-z));
}

// ---------------- scanA (blocks 0..511) + prep (blocks 512..4639) ----------
__global__ __launch_bounds__(256) void k_scanA(
    const float* __restrict__ x,
    const float* __restrict__ fgs, const float* __restrict__ fvs,
    const float* __restrict__ sgs, const float* __restrict__ svs,
    const float* __restrict__ fow, const float* __restrict__ sow,
    const float* __restrict__ mw,  const float* __restrict__ nw,
    float* __restrict__ PF, float* __restrict__ HF,
    float* __restrict__ PS, float* __restrict__ HS,
    unsigned short* __restrict__ wcat, unsigned short* __restrict__ w2,
    float* __restrict__ rowsum) {
  if (blockIdx.x >= 512) {                 // ---- prep part ----
    int g = (blockIdx.x - 512) * 256 + threadIdx.x;   // 0..1056767
    if (g < 524288) {
      int i = g * 4;
      const float* src = (i < 1048576) ? (fow + i) : (sow + (i - 1048576));
      f32x4 v = *(const f32x4*)src;
      ushort4v o = { f2b(v.x), f2b(v.y), f2b(v.z), f2b(v.w) };
      *(ushort4v*)&wcat[i] = o;
    } else if (g < 1048576) {
      int i = (g - 524288) * 4;
      int m = i & 2047;
      f32x4 v = *(const f32x4*)&mw[i];
      f32x4 s = *(const f32x4*)&nw[m];
      ushort4v o = { f2b(v.x * s.x), f2b(v.y * s.y), f2b(v.z * s.z), f2b(v.w * s.w) };
      *(ushort4v*)&w2[i] = o;
    } else if (g < 1056768) {
      rowsum[g - 1048576] = 0.f;
    }
    return;
  }
  // ---- scan part (store-free) ----
  int g = blockIdx.x * 256 + threadIdx.x;   // 0..131071
  int d0 = (g & 511) << 1;
  int rest = g >> 9;
  int chunk = rest & 63, b = rest >> 6;
  float fg0 = 1.f, fg1 = 1.f, fv0 = 1.f, fv1 = 1.f;
  float sg0 = 1.f, sg1 = 1.f, sv0 = 1.f, sv1 = 1.f;
#pragma unroll
  for (int i = 0; i < 5; ++i) {
    f32x2 a = *(const f32x2*)&fgs[i * 1024 + d0]; fg0 *= a.x; fg1 *= a.y;
    f32x2 bq = *(const f32x2*)&fvs[i * 1024 + d0]; fv0 *= bq.x; fv1 *= bq.y;
    f32x2 c = *(const f32x2*)&sgs[i * 1024 + d0]; sg0 *= c.x; sg1 *= c.y;
    f32x2 e = *(const f32x2*)&svs[i * 1024 + d0]; sv0 *= e.x; sv1 *= e.y;
  }
  size_t base = ((size_t)(b * 2048 + chunk * 32)) * 1024 + d0;
  float pF0 = 1.f, hF0 = 0.f, pS0 = 1.f, hS0 = 0.f;
  float pF1 = 1.f, hF1 = 0.f, pS1 = 1.f, hS1 = 0.f;
#pragma unroll 8
  for (int t = 0; t < 32; ++t) {
    f32x2 xv = *(const f32x2*)&x[base + (size_t)t * 1024];
    float fF0 = sigmoidf_(xv.x * fg0 + 0.5f);
    hF0 = fF0 * hF0 + (1.f - fF0) * (xv.x * fv0); pF0 *= fF0;
    float fS0 = 0.85f + 0.15f * sigmoidf_(xv.x * sg0 + 0.5f);
    hS0 = fS0 * hS0 + (1.f - fS0) * (xv.x * sv0); pS0 *= fS0;
    float fF1 = sigmoidf_(xv.y * fg1 + 0.5f);
    hF1 = fF1 * hF1 + (1.f - fF1) * (xv.y * fv1); pF1 *= fF1;
    float fS1 = 0.85f + 0.15f * sigmoidf_(xv.y * sg1 + 0.5f);
    hS1 = fS1 * hS1 + (1.f - fS1) * (xv.y * sv1); pS1 *= fS1;
  }
  int idx = (b * 64 + chunk) * 1024 + d0;
  *(f32x2*)&PF[idx] = f32x2{pF0, pF1};
  *(f32x2*)&HF[idx] = f32x2{hF0, hF1};
  *(f32x2*)&PS[idx] = f32x2{pS0, pS1};
  *(f32x2*)&HS[idx] = f32x2{hS0, hS1};
}

// ---------------- scanC: carry prefix + rescan -> xb (bf16), hcat ----------
__global__ __launch_bounds__(256) void k_scanC(
    const float* __restrict__ x,
    const float* __restrict__ fgs, const float* __restrict__ fvs,
    const float* __restrict__ sgs, const float* __restrict__ svs,
    const float* __restrict__ PF, const float* __restrict__ HF,
    const float* __restrict__ PS, const float* __restrict__ HS,
    unsigned short* __restrict__ xb, unsigned short* __restrict__ hcat) {
  int g = blockIdx.x * 256 + threadIdx.x;
  int d0 = (g & 511) << 1;
  int rest = g >> 9;
  int chunk = rest & 63, b = rest >> 6;   // block-uniform
  float fg0 = 1.f, fg1 = 1.f, fv0 = 1.f, fv1 = 1.f;
  float sg0 = 1.f, sg1 = 1.f, sv0 = 1.f, sv1 = 1.f;
#pragma unroll
  for (int i = 0; i < 5; ++i) {
    f32x2 a = *(const f32x2*)&fgs[i * 1024 + d0]; fg0 *= a.x; fg1 *= a.y;
    f32x2 bq = *(const f32x2*)&fvs[i * 1024 + d0]; fv0 *= bq.x; fv1 *= bq.y;
    f32x2 c = *(const f32x2*)&sgs[i * 1024 + d0]; sg0 *= c.x; sg1 *= c.y;
    f32x2 e = *(const f32x2*)&svs[i * 1024 + d0]; sv0 *= e.x; sv1 *= e.y;
  }
  float cF0 = 0.f, cF1 = 0.f, cS0 = 0.f, cS1 = 0.f;
  {
    int base_i = b * 64 * 1024 + d0;
    int c = 0;
    for (; c + 4 <= chunk; c += 4) {
      f32x2 pf[4], hf[4], ps[4], hs[4];
#pragma unroll
      for (int j = 0; j < 4; ++j) {
        int i = base_i + (c + j) * 1024;
        pf[j] = *(const f32x2*)&PF[i]; hf[j] = *(const f32x2*)&HF[i];
        ps[j] = *(const f32x2*)&PS[i]; hs[j] = *(const f32x2*)&HS[i];
      }
#pragma unroll
      for (int j = 0; j < 4; ++j) {
        cF0 = hf[j].x + pf[j].x * cF0; cF1 = hf[j].y + pf[j].y * cF1;
        cS0 = hs[j].x + ps[j].x * cS0; cS1 = hs[j].y + ps[j].y * cS1;
      }
    }
    for (; c < chunk; ++c) {
      int i = base_i + c * 1024;
      f32x2 pf = *(const f32x2*)&PF[i], hf = *(const f32x2*)&HF[i];
      f32x2 ps = *(const f32x2*)&PS[i], hs = *(const f32x2*)&HS[i];
      cF0 = hf.x + pf.x * cF0; cF1 = hf.y + pf.y * cF1;
      cS0 = hs.x + ps.x * cS0; cS1 = hs.y + ps.y * cS1;
    }
  }
  size_t base = ((size_t)(b * 2048 + chunk * 32)) * 1024 + d0;
  float pF0 = 1.f, hF0 = 0.f, pS0 = 1.f, hS0 = 0.f;
  float pF1 = 1.f, hF1 = 0.f, pS1 = 1.f, hS1 = 0.f;
#pragma unroll 4
  for (int t = 0; t < 32; ++t) {
    f32x2 xv = *(const f32x2*)&x[base + (size_t)t * 1024];
    *(ushort2v*)&xb[base + (size_t)t * 1024] = ushort2v{f2b(xv.x), f2b(xv.y)};
    float fF0 = sigmoidf_(xv.x * fg0 + 0.5f);
    hF0 = fF0 * hF0 + (1.f - fF0) * (xv.x * fv0); pF0 *= fF0;
    float fS0 = 0.85f + 0.15f * sigmoidf_(xv.x * sg0 + 0.5f);
    hS0 = fS0 * hS0 + (1.f - fS0) * (xv.x * sv0); pS0 *= fS0;
    float fF1 = sigmoidf_(xv.y * fg1 + 0.5f);
    hF1 = fF1 * hF1 + (1.f - fF1) * (xv.y * fv1); pF1 *= fF1;
    float fS1 = 0.85f + 0.15f * sigmoidf_(xv.y * sg1 + 0.5f);
    hS1 = fS1 * hS1 + (1.f - fS1) * (xv.y * sv1); pS1 *= fS1;
    size_t bt = (size_t)(b * 2048 + chunk * 32 + t);
    *(ushort2v*)&hcat[bt * 2048 + d0] =
        ushort2v{f2b(hF0 + pF0 * cF0), f2b(hF1 + pF1 * cF1)};
    *(ushort2v*)&hcat[bt * 2048 + 1024 + d0] =
        ushort2v{f2b(hS0 + pS0 * cS0), f2b(hS1 + pS1 * cS1)};
  }
}

// ------------------- 8-phase bf16 MFMA GEMM, BM=256, BK=64 -----------------
// C[m,n] = sum_k A[m,k]*B[n,k].  BN = 64*BT (BT=4 -> 256, BT=2 -> 128).
// 8 waves, 2M x 4N; wave tile 128 x (16*BT); per K-tile 4 phases:
//   P0: ds_read A m0-3 + B n0..NH-1 ; stage A(t+1).h0 ; MFMA m0-3 x nlo
//   P1: ds_read B nNH..BT-1         ; stage A(t+1).h1 ; MFMA m0-3 x nhi
//   P2: ds_read A m4-7              ; stage B(t+2).h0 ; MFMA m4-7 x nhi
//   P3: (regs only)                 ; stage B(t+2).h1 ; MFMA m4-7 x nlo
// Boundary (end P3): s_waitcnt vmcnt(BT) (counted, never 0 in steady state):
// outstanding FIFO there = [B(t+1):BT, A(t+1):4, B(t+2):BT]; vmcnt(BT)
// drains exactly tile t+1's data. Deadness: A halves dead after P2.b2 (other
// buffer anyway), B.h0/h1 dead after P1.b2 -> P2/P3 staging into the SAME
// buffer is safe (all waves past P1.b2 when cp16 issues).
// LDS swizzle: 16B slot = chunk ^ (row&7), rows stride 128B (verified
// conflict-free in prior rounds, SQ_LDS_BANK_CONFLICT = 0).
// MODE 1: merged = bf16(sigmoid(C)*hcat); rowsum[m] += sum v^2 (atomic)
// MODE 2: out = rsqrt(rowsum[m]/2048 + 1e-6) * C
template <int BT, int MODE>
__global__ __launch_bounds__(512, 2) void k_gemm8(
    const unsigned short* __restrict__ A, const unsigned short* __restrict__ B,
    const int K,
    const unsigned short* __restrict__ hcat, unsigned short* __restrict__ merged,
    float* __restrict__ rowsum, float* __restrict__ out) {
  constexpr int BN = 64 * BT;
  constexpr int NH = BT / 2;
  __shared__ __align__(16) unsigned short sA[2][256 * 64];
  __shared__ __align__(16) unsigned short sB[2][BN * 64];

  const int tid = threadIdx.x;
  const int wv = tid >> 6, ln = tid & 63;
  const int wm = wv >> 2, wn = wv & 3;
  const int fr = ln & 15, fq = ln >> 4;
  const int sl0 = (fq ^ (fr & 7)) * 8;          // k-sub 0 slot (elem offset)
  const int sl1 = ((fq + 4) ^ (fr & 7)) * 8;    // k-sub 1
  const int rA = (wm * 128 + fr) * 64;          // elem offset of frag row 0
  const int rB = (wn * 16 * BT + fr) * 64;

  // XCD swizzle: 256 blocks, 8 XCDs -> each XCD gets 4 contiguous M-bands.
  const int swz = (blockIdx.x & 7) * 32 + (blockIdx.x >> 3);
  const int bm = (swz >> 3) * 256;
  const int bn = (swz & 7) * BN;

  // staging addresses (global src pre-swizzled, LDS dest linear lane*16)
  const int srow = tid >> 3, sc = tid & 7;
  const int clog = (sc ^ (srow & 7)) * 8;
  const unsigned short* pA[4]; int lofA[4];
#pragma unroll
  for (int j = 0; j < 4; ++j) {
    pA[j] = A + (size_t)(bm + j * 64 + srow) * K + clog;
    lofA[j] = (j * 64 + srow) * 64 + sc * 8;
  }
  const unsigned short* pB[BT]; int lofB[BT];
#pragma unroll
  for (int j = 0; j < BT; ++j) {
    pB[j] = B + (size_t)(bn + j * 64 + srow) * K + clog;
    lofB[j] = (j * 64 + srow) * 64 + sc * 8;
  }

  f32x4 acc[8][BT];
  const f32x4 z4 = {0.f, 0.f, 0.f, 0.f};
#pragma unroll
  for (int i = 0; i < 8; ++i)
#pragma unroll
    for (int j = 0; j < BT; ++j) acc[i][j] = z4;

  const int NT = K >> 6;
  // ---- prologue: stage tile0 fully + tile1 B halves; wait tile0 ----
#pragma unroll
  for (int j = 0; j < 4; ++j) cp16(pA[j], &sA[0][lofA[j]]);
#pragma unroll
  for (int j = 0; j < BT; ++j) cp16(pB[j], &sB[0][lofB[j]]);
#pragma unroll
  for (int j = 0; j < BT; ++j) cp16(pB[j] + 64, &sB[1][lofB[j]]);
  if constexpr (BT == 4) asm volatile("s_waitcnt vmcnt(4)" ::: "memory");
  else                   asm volatile("s_waitcnt vmcnt(2)" ::: "memory");
  __builtin_amdgcn_s_barrier();
  __builtin_amdgcn_sched_barrier(0);

  for (int t = 0; t < NT; ++t) {
    const unsigned short* cA = &sA[t & 1][0];
    const unsigned short* cB = &sB[t & 1][0];
    unsigned short* dA = &sA[(t + 1) & 1][0];   // A(t+1) dest (other buffer)
    unsigned short* dB = &sB[t & 1][0];         // B(t+2) dest (same parity)
    const size_t ko1 = (size_t)(t + 1) * 64;
    const size_t ko2 = (size_t)(t + 2) * 64;
    short8 af[2][4], bf0[2][NH], bf1[2][NH];
    // ---------------- P0 ----------------
#pragma unroll
    for (int m = 0; m < 4; ++m) {
      af[0][m] = *(const short8*)&cA[rA + m * 1024 + sl0];
      af[1][m] = *(const short8*)&cA[rA + m * 1024 + sl1];
    }
#pragma unroll
    for (int n = 0; n < NH; ++n) {
      bf0[0][n] = *(const short8*)&cB[rB + n * 1024 + sl0];
      bf0[1][n] = *(const short8*)&cB[rB + n * 1024 + sl1];
    }
    if (t + 1 < NT) { cp16(pA[0] + ko1, &dA[lofA[0]]);
                      cp16(pA[1] + ko1, &dA[lofA[1]]); }
    __builtin_amdgcn_s_barrier();
    __builtin_amdgcn_s_setprio(1);
#pragma unroll
    for (int m = 0; m < 4; ++m)
#pragma unroll
      for (int n = 0; n < NH; ++n) {
        acc[m][n] = __builtin_amdgcn_mfma_f32_16x16x32_bf16(af[0][m], bf0[0][n], acc[m][n], 0, 0, 0);
        acc[m][n] = __builtin_amdgcn_mfma_f32_16x16x32_bf16(af[1][m], bf0[1][n], acc[m][n], 0, 0, 0);
      }
    __builtin_amdgcn_s_setprio(0);
    __builtin_amdgcn_s_barrier();
    // ---------------- P1 ----------------
#pragma unroll
    for (int n = 0; n < NH; ++n) {
      bf1[0][n] = *(const short8*)&cB[rB + (NH + n) * 1024 + sl0];
      bf1[1][n] = *(const short8*)&cB[rB + (NH + n) * 1024 + sl1];
    }
    if (t + 1 < NT) { cp16(pA[2] + ko1, &dA[lofA[2]]);
                      cp16(pA[3] + ko1, &dA[lofA[3]]); }
    __builtin_amdgcn_s_barrier();
    __builtin_amdgcn_s_setprio(1);
#pragma unroll
    for (int m = 0; m < 4; ++m)
#pragma unroll
      for (int n = 0; n < NH; ++n) {
        acc[m][NH + n] = __builtin_amdgcn_mfma_f32_16x16x32_bf16(af[0][m], bf1[0][n], acc[m][NH + n], 0, 0, 0);
        acc[m][NH + n] = __builtin_amdgcn_mfma_f32_16x16x32_bf16(af[1][m], bf1[1][n], acc[m][NH + n], 0, 0, 0);
      }
    __builtin_amdgcn_s_setprio(0);
    __builtin_amdgcn_s_barrier();
    // ---------------- P2 ----------------
#pragma unroll
    for (int m = 0; m < 4; ++m) {
      af[0][m] = *(const short8*)&cA[rA + (4 + m) * 1024 + sl0];
      af[1][m] = *(const short8*)&cA[rA + (4 + m) * 1024 + sl1];
    }
    if (t + 2 < NT) {
#pragma unroll
      for (int j = 0; j < NH; ++j) cp16(pB[j] + ko2, &dB[lofB[j]]);
    }
    __builtin_amdgcn_s_barrier();
    __builtin_amdgcn_s_setprio(1);
#pragma unroll
    for (int m = 0; m < 4; ++m)
#pragma unroll
      for (int n = 0; n < NH; ++n) {
        acc[4 + m][NH + n] = __builtin_amdgcn_mfma_f32_16x16x32_bf16(af[0][m], bf1[0][n], acc[4 + m][NH + n], 0, 0, 0);
        acc[4 + m][NH + n] = __builtin_amdgcn_mfma_f32_16x16x32_bf16(af[1][m], bf1[1][n], acc[4 + m][NH + n], 0, 0, 0);
      }
    __builtin_amdgcn_s_setprio(0);
    __builtin_amdgcn_s_barrier();
    // ---------------- P3 ----------------
    if (t + 2 < NT) {
#pragma unroll
      for (int j = NH; j < BT; ++j) cp16(pB[j] + ko2, &dB[lofB[j]]);
    }
    __builtin_amdgcn_s_barrier();
    __builtin_amdgcn_s_setprio(1);
#pragma unroll
    for (int m = 0; m < 4; ++m)
#pragma unroll
      for (int n = 0; n < NH; ++n) {
        acc[4 + m][n] = __builtin_amdgcn_mfma_f32_16x16x32_bf16(af[0][m], bf0[0][n], acc[4 + m][n], 0, 0, 0);
        acc[4 + m][n] = __builtin_amdgcn_mfma_f32_16x16x32_bf16(af[1][m], bf0[1][n], acc[4 + m][n], 0, 0, 0);
      }
    __builtin_amdgcn_s_setprio(0);
    // ---- tile boundary: counted drain (never 0 in steady state) ----
    if (t < NT - 2) {
      if constexpr (BT == 4) asm volatile("s_waitcnt vmcnt(4)" ::: "memory");
      else                   asm volatile("s_waitcnt vmcnt(2)" ::: "memory");
    } else if (t == NT - 2) {
      asm volatile("s_waitcnt vmcnt(0)" ::: "memory");
    }
    __builtin_amdgcn_s_barrier();
    __builtin_amdgcn_sched_barrier(0);
  }

  // C/D layout: col = lane&15, row = (lane>>4)*4 + reg   [verified m89/m91]
  const int er0 = fq * 4;
  if (MODE == 1) {
#pragma unroll
    for (int mi = 0; mi < 8; ++mi) {
#pragma unroll
      for (int r = 0; r < 4; ++r) {
        const int m = bm + wm * 128 + mi * 16 + er0 + r;
        float s = 0.f;
#pragma unroll
        for (int ni = 0; ni < BT; ++ni) {
          const int n = bn + wn * 16 * BT + ni * 16 + fr;
          const size_t idx = (size_t)m * 2048 + n;
          float v = sigmoidf_(acc[mi][ni][r]) * b2f(hcat[idx]);
          merged[idx] = f2b(v);
          s += v * v;
        }
        s += __shfl_xor(s, 1); s += __shfl_xor(s, 2);
        s += __shfl_xor(s, 4); s += __shfl_xor(s, 8);
        if (fr == 0) atomicAdd(&rowsum[m], s);
      }
    }
  } else {
#pragma unroll
    for (int mi = 0; mi < 8; ++mi) {
#pragma unroll
      for (int r = 0; r < 4; ++r) {
        const int m = bm + wm * 128 + mi * 16 + er0 + r;
        const float rf = rsqrtf(rowsum[m] * (1.0f / 2048.0f) + 1e-6f);
#pragma unroll
        for (int ni = 0; ni < BT; ++ni) {
          const int n = bn + wn * 16 * BT + ni * 16 + fr;
          out[(size_t)m * 1024 + n] = rf * acc[mi][ni][r];
        }
      }
    }
  }
}

// ---------------------------------------------------------------------------
extern "C" void kernel_launch(void* const* d_in, const int* in_sizes, int n_in,
                              void* d_out, int out_size, void* d_ws, size_t ws_size,
                              hipStream_t stream) {
  const float* x   = (const float*)d_in[0];
  const float* fgs = (const float*)d_in[1];
  const float* fvs = (const float*)d_in[2];
  const float* fow = (const float*)d_in[3];
  const float* sgs = (const float*)d_in[4];
  const float* svs = (const float*)d_in[5];
  const float* sow = (const float*)d_in[6];
  const float* mw  = (const float*)d_in[7];
  const float* nw  = (const float*)d_in[8];
  float* out = (float*)d_out;

  char* ws = (char*)d_ws;
  float* rowsum = (float*)(ws + 0);                         // 32 KB
  unsigned short* xb   = (unsigned short*)(ws + 32768);     // 16 MB
  unsigned short* wcat = (unsigned short*)(ws + 16809984);  // 4 MB
  unsigned short* w2   = (unsigned short*)(ws + 21004288);  // 4 MB
  unsigned short* hcat = (unsigned short*)(ws + 25198592);  // 32 MB
  unsigned short* mg   = (unsigned short*)(ws + 58753024);  // 32 MB (end ~92MB)
  // P/H (1 MB each) alias the mg region: P/H are dead before GEMM1 writes mg.
  float* PF = (float*)(ws + 58753024);
  float* HF = (float*)(ws + 58753024 + 1 * 1048576);
  float* PS = (float*)(ws + 58753024 + 2 * 1048576);
  float* HS = (float*)(ws + 58753024 + 3 * 1048576);

  // scan (blocks 0..511, store-free) + weight prep (blocks 512..4639)
  k_scanA<<<4640, 256, 0, stream>>>(x, fgs, fvs, sgs, svs, fow, sow, mw, nw,
                                    PF, HF, PS, HS, wcat, w2, rowsum);
  k_scanC<<<512, 256, 0, stream>>>(x, fgs, fvs, sgs, svs, PF, HF, PS, HS,
                                   xb, hcat);
  // GEMM1: M=8192, N=2048, K=1024; tiles 256x256; 32 bands x 8 cols
  k_gemm8<4, 1><<<256, 512, 0, stream>>>(
      xb, wcat, 1024, hcat, mg, rowsum, nullptr);
  // GEMM2: M=8192, N=1024, K=2048; tiles 256x128; 32 bands x 8 cols
  k_gemm8<2, 2><<<256, 512, 0, stream>>>(
      mg, w2, 2048, nullptr, nullptr, rowsum, out);
}

// Round 2
// 221.670 us; speedup vs baseline: 1.0281x; 1.0098x over previous
//
#include <hip/hip_runtime.h>
#include <stdint.h>

// ---------------------------------------------------------------------------
// DualGatedRecurrence on MI355X.
// fwht() in the reference is the identity for D=1024 => hproj(x,s) = x*prod(s).
// Pipeline (4 dispatches):
//   scanA+prep: per-chunk local scans -> P,H aggregates; weight prep to bf16.
//   scanC: carry prefix + full rescan; emits xb (bf16 x) and hcat bf16.
//   GEMM1/GEMM2: 8-phase 256-wide-tile bf16 MFMA schedule. Phases split by
//     (m-half x k-half): 16 independent MFMA per phase, ds_reads balanced
//     8/4/8/4, per-phase asm lgkmcnt(0)+sched_barrier pin (rule #18),
//     counted vmcnt at tile boundary only (T4), setprio around MFMA (T5).
//     GEMM1 epilogue: sigmoid*hcat + rowsum atomics. GEMM2: rsqrt row scale.
// ---------------------------------------------------------------------------

typedef __attribute__((ext_vector_type(8))) short short8;     // 8 bf16
typedef __attribute__((ext_vector_type(4))) float f32x4;
typedef __attribute__((ext_vector_type(2))) float f32x2;
typedef __attribute__((ext_vector_type(4))) unsigned short ushort4v;
typedef __attribute__((ext_vector_type(2))) unsigned short ushort2v;

typedef const __attribute__((address_space(1))) unsigned int* as1_u32p;
typedef __attribute__((address_space(3))) unsigned int* as3_u32p;

__device__ __forceinline__ void cp16(const void* g, void* l) {
  __builtin_amdgcn_global_load_lds((as1_u32p)(uintptr_t)g,
                                   (as3_u32p)(unsigned int)(uintptr_t)l,
                                   16, 0, 0);
}

__device__ __forceinline__ float b2f(unsigned short h) {
  union { unsigned int u; float f; } v; v.u = ((unsigned int)h) << 16; return v.f;
}
__device__ __forceinline__ unsigned short f2b(float f) {
  union { float f; unsigned int u; } v; v.f = f;
  unsigned int r = v.u + 0x7fffu + ((v.u >> 16) & 1u);   // round-nearest-even
  return (unsigned short)(r >> 16);
}
__device__ __forceinline__ float sigmoidf_(float z) {
  return __builtin_amdgcn_rcpf(1.0f + __expf(-z));
}

// ---------------- scanA (blocks 0..511) + prep (blocks 512..4639) ----------
__global__ __launch_bounds__(256) void k_scanA(
    const float* __restrict__ x,
    const float* __restrict__ fgs, const float* __restrict__ fvs,
    const float* __restrict__ sgs, const float* __restrict__ svs,
    const float* __restrict__ fow, const float* __restrict__ sow,
    const float* __restrict__ mw,  const float* __restrict__ nw,
    float* __restrict__ PF, float* __restrict__ HF,
    float* __restrict__ PS, float* __restrict__ HS,
    unsigned short* __restrict__ wcat, unsigned short* __restrict__ w2,
    float* __restrict__ rowsum) {
  if (blockIdx.x >= 512) {                 // ---- prep part ----
    int g = (blockIdx.x - 512) * 256 + threadIdx.x;   // 0..1056767
    if (g < 524288) {
      int i = g * 4;
      const float* src = (i < 1048576) ? (fow + i) : (sow + (i - 1048576));
      f32x4 v = *(const f32x4*)src;
      ushort4v o = { f2b(v.x), f2b(v.y), f2b(v.z), f2b(v.w) };
      *(ushort4v*)&wcat[i] = o;
    } else if (g < 1048576) {
      int i = (g - 524288) * 4;
      int m = i & 2047;
      f32x4 v = *(const f32x4*)&mw[i];
      f32x4 s = *(const f32x4*)&nw[m];
      ushort4v o = { f2b(v.x * s.x), f2b(v.y * s.y), f2b(v.z * s.z), f2b(v.w * s.w) };
      *(ushort4v*)&w2[i] = o;
    } else if (g < 1056768) {
      rowsum[g - 1048576] = 0.f;
    }
    return;
  }
  // ---- scan part (store-free) ----
  int g = blockIdx.x * 256 + threadIdx.x;   // 0..131071
  int d0 = (g & 511) << 1;
  int rest = g >> 9;
  int chunk = rest & 63, b = rest >> 6;
  float fg0 = 1.f, fg1 = 1.f, fv0 = 1.f, fv1 = 1.f;
  float sg0 = 1.f, sg1 = 1.f, sv0 = 1.f, sv1 = 1.f;
#pragma unroll
  for (int i = 0; i < 5; ++i) {
    f32x2 a = *(const f32x2*)&fgs[i * 1024 + d0]; fg0 *= a.x; fg1 *= a.y;
    f32x2 bq = *(const f32x2*)&fvs[i * 1024 + d0]; fv0 *= bq.x; fv1 *= bq.y;
    f32x2 c = *(const f32x2*)&sgs[i * 1024 + d0]; sg0 *= c.x; sg1 *= c.y;
    f32x2 e = *(const f32x2*)&svs[i * 1024 + d0]; sv0 *= e.x; sv1 *= e.y;
  }
  size_t base = ((size_t)(b * 2048 + chunk * 32)) * 1024 + d0;
  float pF0 = 1.f, hF0 = 0.f, pS0 = 1.f, hS0 = 0.f;
  float pF1 = 1.f, hF1 = 0.f, pS1 = 1.f, hS1 = 0.f;
#pragma unroll 8
  for (int t = 0; t < 32; ++t) {
    f32x2 xv = *(const f32x2*)&x[base + (size_t)t * 1024];
    float fF0 = sigmoidf_(xv.x * fg0 + 0.5f);
    hF0 = fF0 * hF0 + (1.f - fF0) * (xv.x * fv0); pF0 *= fF0;
    float fS0 = 0.85f + 0.15f * sigmoidf_(xv.x * sg0 + 0.5f);
    hS0 = fS0 * hS0 + (1.f - fS0) * (xv.x * sv0); pS0 *= fS0;
    float fF1 = sigmoidf_(xv.y * fg1 + 0.5f);
    hF1 = fF1 * hF1 + (1.f - fF1) * (xv.y * fv1); pF1 *= fF1;
    float fS1 = 0.85f + 0.15f * sigmoidf_(xv.y * sg1 + 0.5f);
    hS1 = fS1 * hS1 + (1.f - fS1) * (xv.y * sv1); pS1 *= fS1;
  }
  int idx = (b * 64 + chunk) * 1024 + d0;
  *(f32x2*)&PF[idx] = f32x2{pF0, pF1};
  *(f32x2*)&HF[idx] = f32x2{hF0, hF1};
  *(f32x2*)&PS[idx] = f32x2{pS0, pS1};
  *(f32x2*)&HS[idx] = f32x2{hS0, hS1};
}

// ---------------- scanC: carry prefix + rescan -> xb (bf16), hcat ----------
__global__ __launch_bounds__(256) void k_scanC(
    const float* __restrict__ x,
    const float* __restrict__ fgs, const float* __restrict__ fvs,
    const float* __restrict__ sgs, const float* __restrict__ svs,
    const float* __restrict__ PF, const float* __restrict__ HF,
    const float* __restrict__ PS, const float* __restrict__ HS,
    unsigned short* __restrict__ xb, unsigned short* __restrict__ hcat) {
  int g = blockIdx.x * 256 + threadIdx.x;
  int d0 = (g & 511) << 1;
  int rest = g >> 9;
  int chunk = rest & 63, b = rest >> 6;   // block-uniform
  float fg0 = 1.f, fg1 = 1.f, fv0 = 1.f, fv1 = 1.f;
  float sg0 = 1.f, sg1 = 1.f, sv0 = 1.f, sv1 = 1.f;
#pragma unroll
  for (int i = 0; i < 5; ++i) {
    f32x2 a = *(const f32x2*)&fgs[i * 1024 + d0]; fg0 *= a.x; fg1 *= a.y;
    f32x2 bq = *(const f32x2*)&fvs[i * 1024 + d0]; fv0 *= bq.x; fv1 *= bq.y;
    f32x2 c = *(const f32x2*)&sgs[i * 1024 + d0]; sg0 *= c.x; sg1 *= c.y;
    f32x2 e = *(const f32x2*)&svs[i * 1024 + d0]; sv0 *= e.x; sv1 *= e.y;
  }
  float cF0 = 0.f, cF1 = 0.f, cS0 = 0.f, cS1 = 0.f;
  {
    int base_i = b * 64 * 1024 + d0;
    int c = 0;
    for (; c + 4 <= chunk; c += 4) {
      f32x2 pf[4], hf[4], ps[4], hs[4];
#pragma unroll
      for (int j = 0; j < 4; ++j) {
        int i = base_i + (c + j) * 1024;
        pf[j] = *(const f32x2*)&PF[i]; hf[j] = *(const f32x2*)&HF[i];
        ps[j] = *(const f32x2*)&PS[i]; hs[j] = *(const f32x2*)&HS[i];
      }
#pragma unroll
      for (int j = 0; j < 4; ++j) {
        cF0 = hf[j].x + pf[j].x * cF0; cF1 = hf[j].y + pf[j].y * cF1;
        cS0 = hs[j].x + ps[j].x * cS0; cS1 = hs[j].y + ps[j].y * cS1;
      }
    }
    for (; c < chunk; ++c) {
      int i = base_i + c * 1024;
      f32x2 pf = *(const f32x2*)&PF[i], hf = *(const f32x2*)&HF[i];
      f32x2 ps = *(const f32x2*)&PS[i], hs = *(const f32x2*)&HS[i];
      cF0 = hf.x + pf.x * cF0; cF1 = hf.y + pf.y * cF1;
      cS0 = hs.x + ps.x * cS0; cS1 = hs.y + ps.y * cS1;
    }
  }
  size_t base = ((size_t)(b * 2048 + chunk * 32)) * 1024 + d0;
  float pF0 = 1.f, hF0 = 0.f, pS0 = 1.f, hS0 = 0.f;
  float pF1 = 1.f, hF1 = 0.f, pS1 = 1.f, hS1 = 0.f;
#pragma unroll 4
  for (int t = 0; t < 32; ++t) {
    f32x2 xv = *(const f32x2*)&x[base + (size_t)t * 1024];
    *(ushort2v*)&xb[base + (size_t)t * 1024] = ushort2v{f2b(xv.x), f2b(xv.y)};
    float fF0 = sigmoidf_(xv.x * fg0 + 0.5f);
    hF0 = fF0 * hF0 + (1.f - fF0) * (xv.x * fv0); pF0 *= fF0;
    float fS0 = 0.85f + 0.15f * sigmoidf_(xv.x * sg0 + 0.5f);
    hS0 = fS0 * hS0 + (1.f - fS0) * (xv.x * sv0); pS0 *= fS0;
    float fF1 = sigmoidf_(xv.y * fg1 + 0.5f);
    hF1 = fF1 * hF1 + (1.f - fF1) * (xv.y * fv1); pF1 *= fF1;
    float fS1 = 0.85f + 0.15f * sigmoidf_(xv.y * sg1 + 0.5f);
    hS1 = fS1 * hS1 + (1.f - fS1) * (xv.y * sv1); pS1 *= fS1;
    size_t bt = (size_t)(b * 2048 + chunk * 32 + t);
    *(ushort2v*)&hcat[bt * 2048 + d0] =
        ushort2v{f2b(hF0 + pF0 * cF0), f2b(hF1 + pF1 * cF1)};
    *(ushort2v*)&hcat[bt * 2048 + 1024 + d0] =
        ushort2v{f2b(hS0 + pS0 * cS0), f2b(hS1 + pS1 * cS1)};
  }
}

// ------------------- 8-phase bf16 MFMA GEMM, BM=256, BK=64 -----------------
// C[m,n] = sum_k A[m,k]*B[n,k].  BN = 64*BT (BT=4 -> 256, BT=2 -> 128).
// 8 waves, 2M x 4N; wave tile 128 x (16*BT).  Phases split by (m-half,k-half)
// so each phase = 4m x BT*n x 1 k-half = 4*BT independent MFMAs:
//   Ph0: read aA=A[mlo,k0](4) + b0=B[:,k0](BT) ; stage A(t+1).h0 ; MFMA
//   Ph1: read aB=A[mhi,k0](4)                  ; stage A(t+1).h1 ; MFMA
//   Ph2: read aA=A[mlo,k1](4) + b1=B[:,k1](BT) ; (no stage)      ; MFMA
//   Ph3: read aB=A[mhi,k1](4)                  ; stage B(t+2) all; MFMA
// ds_reads balanced 8/4/8/4 (BT=4).  B(t+2) staged only in Ph3: B(t) reads
// complete at Ph2's post-MFMA barrier, so same-buffer staging is race-free.
// Each phase: reads+stage -> s_barrier -> asm lgkmcnt(0) -> sched_barrier(0)
// (rule #18) -> setprio(1) -> MFMA -> setprio(0) -> s_barrier.
// Boundary (end Ph3): counted vmcnt(BT) (never 0 in steady state): FIFO =
// [B(t+1):BT (t-1.Ph3), A(t+1):4 (Ph0/1), B(t+2):BT (Ph3)] -> drains t+1's
// data exactly.  A waits have ~3 phases of flight time; B ~4: no stall.
// Frag regs double-buffered (aA/aB, b0/b1): all WAR distances >= 2 phases.
// LDS swizzle: 16B slot = chunk ^ (row&7), rows stride 128B (verified
// conflict-free, SQ_LDS_BANK_CONFLICT = 0).
// MODE 1: merged = bf16(sigmoid(C)*hcat); rowsum[m] += sum v^2 (atomic)
// MODE 2: out = rsqrt(rowsum[m]/2048 + 1e-6) * C
template <int BT, int MODE>
__global__ __launch_bounds__(512, 2) void k_gemm8(
    const unsigned short* __restrict__ A, const unsigned short* __restrict__ B,
    const int K,
    const unsigned short* __restrict__ hcat, unsigned short* __restrict__ merged,
    float* __restrict__ rowsum, float* __restrict__ out) {
  constexpr int BN = 64 * BT;
  __shared__ __align__(16) unsigned short sA[2][256 * 64];
  __shared__ __align__(16) unsigned short sB[2][BN * 64];

  const int tid = threadIdx.x;
  const int wv = tid >> 6, ln = tid & 63;
  const int wm = wv >> 2, wn = wv & 3;
  const int fr = ln & 15, fq = ln >> 4;
  const int sl0 = (fq ^ (fr & 7)) * 8;          // k-half 0 slot (elem offset)
  const int sl1 = ((fq + 4) ^ (fr & 7)) * 8;    // k-half 1
  const int rA = (wm * 128 + fr) * 64;          // elem offset of frag row 0
  const int rB = (wn * 16 * BT + fr) * 64;

  // XCD swizzle: 256 blocks, 8 XCDs -> each XCD gets 4 contiguous M-bands.
  const int swz = (blockIdx.x & 7) * 32 + (blockIdx.x >> 3);
  const int bm = (swz >> 3) * 256;
  const int bn = (swz & 7) * BN;

  // staging addresses (global src pre-swizzled, LDS dest linear lane*16)
  const int srow = tid >> 3, sc = tid & 7;
  const int clog = (sc ^ (srow & 7)) * 8;
  const unsigned short* pA[4]; int lofA[4];
#pragma unroll
  for (int j = 0; j < 4; ++j) {
    pA[j] = A + (size_t)(bm + j * 64 + srow) * K + clog;
    lofA[j] = (j * 64 + srow) * 64 + sc * 8;
  }
  const unsigned short* pB[BT]; int lofB[BT];
#pragma unroll
  for (int j = 0; j < BT; ++j) {
    pB[j] = B + (size_t)(bn + j * 64 + srow) * K + clog;
    lofB[j] = (j * 64 + srow) * 64 + sc * 8;
  }

  f32x4 acc[8][BT];
  const f32x4 z4 = {0.f, 0.f, 0.f, 0.f};
#pragma unroll
  for (int i = 0; i < 8; ++i)
#pragma unroll
    for (int j = 0; j < BT; ++j) acc[i][j] = z4;

  const int NT = K >> 6;
  // ---- prologue: stage tile0 fully + tile1 B; wait tile0 (leave B1) ----
#pragma unroll
  for (int j = 0; j < 4; ++j) cp16(pA[j], &sA[0][lofA[j]]);
#pragma unroll
  for (int j = 0; j < BT; ++j) cp16(pB[j], &sB[0][lofB[j]]);
#pragma unroll
  for (int j = 0; j < BT; ++j) cp16(pB[j] + 64, &sB[1][lofB[j]]);
  if constexpr (BT == 4) asm volatile("s_waitcnt vmcnt(4)" ::: "memory");
  else                   asm volatile("s_waitcnt vmcnt(2)" ::: "memory");
  __builtin_amdgcn_s_barrier();
  __builtin_amdgcn_sched_barrier(0);

  for (int t = 0; t < NT; ++t) {
    const unsigned short* cA = &sA[t & 1][0];
    const unsigned short* cB = &sB[t & 1][0];
    unsigned short* dA = &sA[(t + 1) & 1][0];   // A(t+1) dest (other buffer)
    unsigned short* dB = &sB[t & 1][0];         // B(t+2) dest (same parity)
    const size_t ko1 = (size_t)(t + 1) * 64;
    const size_t ko2 = (size_t)(t + 2) * 64;
    short8 aA[4], aB[4], b0[BT], b1[BT];
    // ---------------- Ph0: A[mlo,k0] + B[:,k0] ----------------
#pragma unroll
    for (int m = 0; m < 4; ++m) aA[m] = *(const short8*)&cA[rA + m * 1024 + sl0];
#pragma unroll
    for (int n = 0; n < BT; ++n) b0[n] = *(const short8*)&cB[rB + n * 1024 + sl0];
    if (t + 1 < NT) { cp16(pA[0] + ko1, &dA[lofA[0]]);
                      cp16(pA[1] + ko1, &dA[lofA[1]]); }
    __builtin_amdgcn_s_barrier();
    asm volatile("s_waitcnt lgkmcnt(0)" ::: "memory");
    __builtin_amdgcn_sched_barrier(0);
    __builtin_amdgcn_s_setprio(1);
#pragma unroll
    for (int m = 0; m < 4; ++m)
#pragma unroll
      for (int n = 0; n < BT; ++n)
        acc[m][n] = __builtin_amdgcn_mfma_f32_16x16x32_bf16(aA[m], b0[n], acc[m][n], 0, 0, 0);
    __builtin_amdgcn_s_setprio(0);
    __builtin_amdgcn_s_barrier();
    // ---------------- Ph1: A[mhi,k0] ----------------
#pragma unroll
    for (int m = 0; m < 4; ++m) aB[m] = *(const short8*)&cA[rA + (4 + m) * 1024 + sl0];
    if (t + 1 < NT) { cp16(pA[2] + ko1, &dA[lofA[2]]);
                      cp16(pA[3] + ko1, &dA[lofA[3]]); }
    __builtin_amdgcn_s_barrier();
    asm volatile("s_waitcnt lgkmcnt(0)" ::: "memory");
    __builtin_amdgcn_sched_barrier(0);
    __builtin_amdgcn_s_setprio(1);
#pragma unroll
    for (int m = 0; m < 4; ++m)
#pragma unroll
      for (int n = 0; n < BT; ++n)
        acc[4 + m][n] = __builtin_amdgcn_mfma_f32_16x16x32_bf16(aB[m], b0[n], acc[4 + m][n], 0, 0, 0);
    __builtin_amdgcn_s_setprio(0);
    __builtin_amdgcn_s_barrier();
    // ---------------- Ph2: A[mlo,k1] + B[:,k1] ----------------
#pragma unroll
    for (int m = 0; m < 4; ++m) aA[m] = *(const short8*)&cA[rA + m * 1024 + sl1];
#pragma unroll
    for (int n = 0; n < BT; ++n) b1[n] = *(const short8*)&cB[rB + n * 1024 + sl1];
    __builtin_amdgcn_s_barrier();
    asm volatile("s_waitcnt lgkmcnt(0)" ::: "memory");
    __builtin_amdgcn_sched_barrier(0);
    __builtin_amdgcn_s_setprio(1);
#pragma unroll
    for (int m = 0; m < 4; ++m)
#pragma unroll
      for (int n = 0; n < BT; ++n)
        acc[m][n] = __builtin_amdgcn_mfma_f32_16x16x32_bf16(aA[m], b1[n], acc[m][n], 0, 0, 0);
    __builtin_amdgcn_s_setprio(0);
    __builtin_amdgcn_s_barrier();
    // ---------------- Ph3: A[mhi,k1] ; stage B(t+2) ----------------
#pragma unroll
    for (int m = 0; m < 4; ++m) aB[m] = *(const short8*)&cA[rA + (4 + m) * 1024 + sl1];
    if (t + 2 < NT) {
#pragma unroll
      for (int j = 0; j < BT; ++j) cp16(pB[j] + ko2, &dB[lofB[j]]);
    }
    __builtin_amdgcn_s_barrier();
    asm volatile("s_waitcnt lgkmcnt(0)" ::: "memory");
    __builtin_amdgcn_sched_barrier(0);
    __builtin_amdgcn_s_setprio(1);
#pragma unroll
    for (int m = 0; m < 4; ++m)
#pragma unroll
      for (int n = 0; n < BT; ++n)
        acc[4 + m][n] = __builtin_amdgcn_mfma_f32_16x16x32_bf16(aB[m], b1[n], acc[4 + m][n], 0, 0, 0);
    __builtin_amdgcn_s_setprio(0);
    // ---- tile boundary: counted drain (never 0 in steady state) ----
    if (t < NT - 2) {
      if constexpr (BT == 4) asm volatile("s_waitcnt vmcnt(4)" ::: "memory");
      else                   asm volatile("s_waitcnt vmcnt(2)" ::: "memory");
    } else if (t == NT - 2) {
      asm volatile("s_waitcnt vmcnt(0)" ::: "memory");
    }
    __builtin_amdgcn_s_barrier();
    __builtin_amdgcn_sched_barrier(0);
  }

  // C/D layout: col = lane&15, row = (lane>>4)*4 + reg   [verified m89/m91]
  const int er0 = fq * 4;
  if (MODE == 1) {
#pragma unroll
    for (int mi = 0; mi < 8; ++mi) {
#pragma unroll
      for (int r = 0; r < 4; ++r) {
        const int m = bm + wm * 128 + mi * 16 + er0 + r;
        float s = 0.f;
#pragma unroll
        for (int ni = 0; ni < BT; ++ni) {
          const int n = bn + wn * 16 * BT + ni * 16 + fr;
          const size_t idx = (size_t)m * 2048 + n;
          float v = sigmoidf_(acc[mi][ni][r]) * b2f(hcat[idx]);
          merged[idx] = f2b(v);
          s += v * v;
        }
        s += __shfl_xor(s, 1); s += __shfl_xor(s, 2);
        s += __shfl_xor(s, 4); s += __shfl_xor(s, 8);
        if (fr == 0) atomicAdd(&rowsum[m], s);
      }
    }
  } else {
#pragma unroll
    for (int mi = 0; mi < 8; ++mi) {
#pragma unroll
      for (int r = 0; r < 4; ++r) {
        const int m = bm + wm * 128 + mi * 16 + er0 + r;
        const float rf = rsqrtf(rowsum[m] * (1.0f / 2048.0f) + 1e-6f);
#pragma unroll
        for (int ni = 0; ni < BT; ++ni) {
          const int n = bn + wn * 16 * BT + ni * 16 + fr;
          out[(size_t)m * 1024 + n] = rf * acc[mi][ni][r];
        }
      }
    }
  }
}

// ---------------------------------------------------------------------------
extern "C" void kernel_launch(void* const* d_in, const int* in_sizes, int n_in,
                              void* d_out, int out_size, void* d_ws, size_t ws_size,
                              hipStream_t stream) {
  const float* x   = (const float*)d_in[0];
  const float* fgs = (const float*)d_in[1];
  const float* fvs = (const float*)d_in[2];
  const float* fow = (const float*)d_in[3];
  const float* sgs = (const float*)d_in[4];
  const float* svs = (const float*)d_in[5];
  const float* sow = (const float*)d_in[6];
  const float* mw  = (const float*)d_in[7];
  const float* nw  = (const float*)d_in[8];
  float* out = (float*)d_out;

  char* ws = (char*)d_ws;
  float* rowsum = (float*)(ws + 0);                         // 32 KB
  unsigned short* xb   = (unsigned short*)(ws + 32768);     // 16 MB
  unsigned short* wcat = (unsigned short*)(ws + 16809984);  // 4 MB
  unsigned short* w2   = (unsigned short*)(ws + 21004288);  // 4 MB
  unsigned short* hcat = (unsigned short*)(ws + 25198592);  // 32 MB
  unsigned short* mg   = (unsigned short*)(ws + 58753024);  // 32 MB (end ~92MB)
  // P/H (1 MB each) alias the mg region: P/H are dead before GEMM1 writes mg.
  float* PF = (float*)(ws + 58753024);
  float* HF = (float*)(ws + 58753024 + 1 * 1048576);
  float* PS = (float*)(ws + 58753024 + 2 * 1048576);
  float* HS = (float*)(ws + 58753024 + 3 * 1048576);

  // scan (blocks 0..511, store-free) + weight prep (blocks 512..4639)
  k_scanA<<<4640, 256, 0, stream>>>(x, fgs, fvs, sgs, svs, fow, sow, mw, nw,
                                    PF, HF, PS, HS, wcat, w2, rowsum);
  k_scanC<<<512, 256, 0, stream>>>(x, fgs, fvs, sgs, svs, PF, HF, PS, HS,
                                   xb, hcat);
  // GEMM1: M=8192, N=2048, K=1024; tiles 256x256; 32 bands x 8 cols
  k_gemm8<4, 1><<<256, 512, 0, stream>>>(
      xb, wcat, 1024, hcat, mg, rowsum, nullptr);
  // GEMM2: M=8192, N=1024, K=2048; tiles 256x128; 32 bands x 8 cols
  k_gemm8<2, 2><<<256, 512, 0, stream>>>(
      mg, w2, 2048, nullptr, nullptr, rowsum, out);
}